// Round 6
// baseline (57.555 us; speedup 1.0000x reference)
//
#include <hip/hip_runtime.h>

#define TPB     512
#define LSEQ    1024          // L
#define NCOL    1022          // n = L-2 (columns)
#define NROW    1021          // cumprod rows
#define NPAD    1021          // leading zeros: sp index never < 0
#define SLDS    (NPAD + NCOL) // 2043 floats = 8172 B LDS
#define NCHUNK  8
#define RPC     128           // rows per chunk (last chunk: 125)

typedef float v2f __attribute__((ext_vector_type(2)));

// Each 512-thread block owns ONE contiguous output region: (bd, rows
// [128c, 128c+128)). 128 rows x 4088 B = 523264 B == 0 mod 128, so chunk
// boundaries are cache-line aligned -> no L2 line is shared between blocks
// (single-owner regions; partial wave-store edges merge in the block's own
// XCD L2). Thread t owns columns (2t, 2t+1); v_hi(r+1)==v_lo(r) register
// reuse gives 1 LDS read/row; zero-padded LDS removes all index clamps so
// every lane runs the same uniform trip counts (no divergence). Chunk entry
// accumulators are recomputed by a store-free prefix walk (cheap VALU,
// hidden under the co-resident block's stores).
__global__ __launch_bounds__(TPB) void gate_kernel(
    const float* __restrict__ score,
    const int*   __restrict__ score_idx,
    float*       __restrict__ out)
{
    __shared__ float sp[SLDS];

    const int bid   = blockIdx.x;
    const int chunk = bid & (NCHUNK - 1);
    const int bd    = bid >> 3;          // b*2 + d
    const int d     = bd & 1;
    const int b     = bd >> 1;
    const int tid   = threadIdx.x;

    for (int i = tid; i < NPAD; i += TPB) sp[i] = 0.0f;
    const int* idxRow = score_idx + b * LSEQ + 1;       // docs[b][1:]
    for (int i = tid; i < NCOL; i += TPB) {
        int src = (d == 0) ? i : (NCOL - 1 - i);
        sp[NPAD + i] = score[idxRow[src]];
    }
    __syncthreads();

    const int j0 = tid * 2;
    if (j0 >= NCOL) return;              // tid 511 idle after staging

    const float c0 = 1.0f - 10.0f * sp[NPAD + j0];
    const float c1 = 1.0f - 10.0f * sp[NPAD + j0 + 1];

    float a0 = 1.0f, a1 = 1.0f;
    float vhi = sp[NPAD + j0];           // v for col j0+1 at r=0
    int   m   = NPAD + j0 - 1;           // fresh-read index (col j0), descending

    const int r0 = chunk * RPC;
    const int r1 = (r0 + RPC < NROW) ? r0 + RPC : NROW;

#define STEP(X)                                                             \
    {   float _v = (X);                                                     \
        float _p0 = fminf(fmaxf(__builtin_fmaf(_v,  10.0f, c0), 0.0f), 1.0f); \
        float _p1 = fminf(fmaxf(__builtin_fmaf(vhi, 10.0f, c1), 0.0f), 1.0f); \
        a0 *= _p0; a1 *= _p1; vhi = _v; }

    // ---------- prefix: rows [0, r0), no stores (r0 % 8 == 0) ----------
    #pragma unroll 1
    for (int bt = 0; bt < r0 / 8; ++bt) {
        float x0 = sp[m    ], x1 = sp[m - 1], x2 = sp[m - 2], x3 = sp[m - 3];
        float x4 = sp[m - 4], x5 = sp[m - 5], x6 = sp[m - 6], x7 = sp[m - 7];
        m -= 8;
        STEP(x0); STEP(x1); STEP(x2); STEP(x3);
        STEP(x4); STEP(x5); STEP(x6); STEP(x7);
    }

    // ---------- store loop: rows [r0, r1) ----------
    float* outp = out + (size_t)bd * NROW * NCOL + (size_t)r0 * NCOL + j0;
    const int nrows = r1 - r0;           // 128, or 125 for the last chunk

#define EMIT  { v2f w; w.x = a0; w.y = a1; *(v2f*)outp = w; outp += NCOL; }

    #pragma unroll 1
    for (int bt = 0; bt < nrows / 8; ++bt) {
        float x0 = sp[m    ], x1 = sp[m - 1], x2 = sp[m - 2], x3 = sp[m - 3];
        float x4 = sp[m - 4], x5 = sp[m - 5], x6 = sp[m - 6], x7 = sp[m - 7];
        m -= 8;
        STEP(x0); EMIT; STEP(x1); EMIT; STEP(x2); EMIT; STEP(x3); EMIT;
        STEP(x4); EMIT; STEP(x5); EMIT; STEP(x6); EMIT; STEP(x7); EMIT;
    }
    #pragma unroll 1
    for (int r = nrows & ~7; r < nrows; ++r) {   // tail (5 rows, last chunk)
        float x = sp[m]; --m;
        STEP(x); EMIT;
    }
#undef STEP
#undef EMIT
}

extern "C" void kernel_launch(void* const* d_in, const int* in_sizes, int n_in,
                              void* d_out, int out_size, void* d_ws, size_t ws_size,
                              hipStream_t stream)
{
    const float* score = (const float*)d_in[0];
    const int*   sidx  = (const int*)d_in[1];
    float*       out   = (float*)d_out;

    const int B = in_sizes[0] / LSEQ;    // 32
    dim3 grid(B * 2 * NCHUNK), block(TPB);   // 512 blocks x 512 threads
    gate_kernel<<<grid, block, 0, stream>>>(score, sidx, out);
}

// Round 7
// 49.880 us; speedup vs baseline: 1.1539x; 1.1539x over previous
//
#include <hip/hip_runtime.h>

#define TPB   128
#define LSEQ  1024            // L
#define NCOL  1022            // n = L-2 (columns)
#define NROW  1021            // cumprod rows (= 127*8 + 5)
#define NPAD  1021            // leading zeros: index j-1-r+NPAD never < 0
#define SLDS  (NPAD + NCOL)   // 2043 floats = 8172 B LDS

// One thread owns ONE column j of one (batch, dir) matrix and walks the
// serial cumprod down all 1021 rows. Zero-padded LDS supplies the v=0
// region; batch-8 ds_reads amortize LDS latency.
//
// Block-index decode bid = cb*64 + bd (NOT bd*8 + cb): XCD = bid % 8 =
// bd % 8, so all 8 column-blocks of one (b,d) matrix run on the SAME XCD.
// The 512B column-block boundaries split a 128B cache line on 15/16 rows
// (row stride 4088 = 120 mod 128); same-XCD placement lets those split
// lines merge in one L2 instead of forcing DRAM read-modify-write.
__global__ __launch_bounds__(TPB) void gate_kernel(
    const float* __restrict__ score,
    const int*   __restrict__ score_idx,
    float*       __restrict__ out)
{
    __shared__ float sp[SLDS];

    const int bid = blockIdx.x;
    const int cb  = bid >> 6;           // column block 0..7  (XCD-swizzled)
    const int bd  = bid & 63;           // b*2 + d
    const int d   = bd & 1;
    const int b   = bd >> 1;
    const int tid = threadIdx.x;

    for (int i = tid; i < NPAD; i += TPB) sp[i] = 0.0f;
    const int* idxRow = score_idx + b * LSEQ + 1;      // docs[b][1:]
    for (int i = tid; i < NCOL; i += TPB) {
        int src = (d == 0) ? i : (NCOL - 1 - i);
        sp[NPAD + i] = score[idxRow[src]];
    }
    __syncthreads();

    const int j = cb * TPB + tid;
    if (j >= NCOL) return;              // 2 idle lanes in the last block

    const float c = 1.0f - 10.0f * sp[NPAD + j];
    float a = 1.0f;
    int   m = NPAD + j - 1;             // sp index of v at row r (descending)
    float* outp = out + (size_t)bd * NROW * NCOL + j;

#define ROW(X)                                                              \
    {   float p = fminf(fmaxf(__builtin_fmaf((X), 10.0f, c), 0.0f), 1.0f);  \
        a *= p; *outp = a; outp += NCOL; }

    #pragma unroll 1
    for (int bt = 0; bt < NROW / 8; ++bt) {      // 127 batches
        float x0 = sp[m    ], x1 = sp[m - 1], x2 = sp[m - 2], x3 = sp[m - 3];
        float x4 = sp[m - 4], x5 = sp[m - 5], x6 = sp[m - 6], x7 = sp[m - 7];
        m -= 8;
        ROW(x0); ROW(x1); ROW(x2); ROW(x3);
        ROW(x4); ROW(x5); ROW(x6); ROW(x7);
    }
    // tail: 5 rows
    {
        float x0 = sp[m], x1 = sp[m - 1], x2 = sp[m - 2], x3 = sp[m - 3];
        float x4 = sp[m - 4];
        ROW(x0); ROW(x1); ROW(x2); ROW(x3); ROW(x4);
    }
#undef ROW
}

extern "C" void kernel_launch(void* const* d_in, const int* in_sizes, int n_in,
                              void* d_out, int out_size, void* d_ws, size_t ws_size,
                              hipStream_t stream)
{
    const float* score = (const float*)d_in[0];
    const int*   sidx  = (const int*)d_in[1];
    float*       out   = (float*)d_out;

    const int B = in_sizes[0] / LSEQ;   // 32
    dim3 grid(B * 2 * 8), block(TPB);   // 512 blocks x 128 threads
    gate_kernel<<<grid, block, 0, stream>>>(score, sidx, out);
}

// Round 8
// 44.551 us; speedup vs baseline: 1.2919x; 1.1196x over previous
//
#include <hip/hip_runtime.h>

#define TPB     256
#define LSEQ    1024          // L
#define NCOL    1022          // n = L-2 (columns)
#define NROW    1021          // cumprod rows
#define NPAD    1024          // leading zeros (>=1021; 1024 -> 16B-aligned b128 reads)
#define SLDS    2048          // NPAD + NCOL + 2-entry tail pad = 2048 floats
#define NCHUNK  4
#define RPC     256           // rows per chunk (last: 253)

typedef float v2f __attribute__((ext_vector_type(2)));
typedef float v4f __attribute__((ext_vector_type(4)));

__device__ __forceinline__ float clamp01(float x) {
    return fminf(fmaxf(x, 0.0f), 1.0f);          // v_med3_f32
}

// Each 256-thread block writes ENTIRE 4088B rows of one (b,d) matrix for a
// 256-row chunk: thread t owns columns 4t..4t+3 (float4 store = 1024B/wave).
// Chunk regions are contiguous and 128B-aligned (256*4088 % 128 == 0), so no
// cache line is shared between blocks (except 63 negligible matrix
// boundaries); intra-row splits are same-block/same-CU and merge in L1.
// p(r,j) = clamp01((v - s[j])*10 + 1), v = s[j-1-r] (0 if idx<0, via LDS
// zero-pad). Per row: 1 fresh LDS value + 3 carry regs (4-col window);
// batches of 8 rows use two aligned ds_read_b128. Chunk-entry accumulators
// recomputed by a store-free prefix walk (1.5x VALU total, hidden under BW).
__global__ __launch_bounds__(TPB) void gate_kernel(
    const float* __restrict__ score,
    const int*   __restrict__ score_idx,
    float*       __restrict__ out)
{
    __shared__ __align__(16) float sp[SLDS];

    const int bid = blockIdx.x;
    const int ch  = bid >> 6;            // chunk 0..3 (bid = ch*64 + bd)
    const int bd  = bid & 63;            // b*2 + d    (XCD = bd % 8)
    const int d   = bd & 1;
    const int b   = bd >> 1;
    const int tid = threadIdx.x;

    for (int i = tid; i < NPAD; i += TPB) sp[i] = 0.0f;
    if (tid < 2) sp[NPAD + NCOL + tid] = 0.0f;          // tail pad
    const int* idxRow = score_idx + b * LSEQ + 1;       // docs[b][1:]
    for (int i = tid; i < NCOL; i += TPB) {
        int src = d ? (NCOL - 1 - i) : i;
        sp[NPAD + i] = score[idxRow[src]];
    }
    __syncthreads();

    const int j = tid * 4;               // columns j..j+3 (t=255: j+2,j+3 are pad)
    const float s0 = sp[NPAD + j    ], s1 = sp[NPAD + j + 1];
    const float s2 = sp[NPAD + j + 2], s3 = sp[NPAD + j + 3];
    const float c0 = 1.0f - 10.0f * s0, c1 = 1.0f - 10.0f * s1;
    const float c2 = 1.0f - 10.0f * s2, c3 = 1.0f - 10.0f * s3;

    float a0 = 1.0f, a1 = 1.0f, a2 = 1.0f, a3 = 1.0f;
    float C1 = s0, C2 = s1, C3 = s2;     // carries: v for cols j+1..j+3
    int   m  = NPAD + j - 1;             // fresh-value index (col j), descending

#define STEP(X)                                                     \
    {   float _x = (X);                                             \
        float p0 = clamp01(__builtin_fmaf(_x, 10.0f, c0));          \
        float p1 = clamp01(__builtin_fmaf(C1, 10.0f, c1));          \
        float p2 = clamp01(__builtin_fmaf(C2, 10.0f, c2));          \
        float p3 = clamp01(__builtin_fmaf(C3, 10.0f, c3));          \
        a0 *= p0; a1 *= p1; a2 *= p2; a3 *= p3;                     \
        C3 = C2; C2 = C1; C1 = _x; }

    // ---------- prefix: rows [0, 256*ch), no stores ----------
    #pragma unroll 1
    for (int bt = 0; bt < ch * (RPC / 8); ++bt) {
        v4f hi = *(const v4f*)&sp[m - 3];    // 16B-aligned (NPAD=1024)
        v4f lo = *(const v4f*)&sp[m - 7];
        m -= 8;
        STEP(hi.w); STEP(hi.z); STEP(hi.y); STEP(hi.x);
        STEP(lo.w); STEP(lo.z); STEP(lo.y); STEP(lo.x);
    }

    // ---------- store loop: rows [r0, r1) ----------
    const int r0 = ch * RPC;
    const int r1 = (r0 + RPC < NROW) ? (r0 + RPC) : NROW;
    const int nrows = r1 - r0;           // 256, or 253 for last chunk
    const bool half = (tid == TPB - 1);  // last thread: only 2 real columns

    float* outp = out + (size_t)bd * NROW * NCOL + (size_t)r0 * NCOL + j;

#define EMIT                                                        \
    {   if (half) { v2f w2; w2.x = a0; w2.y = a1;                   \
                    *(v2f*)outp = w2; }                             \
        else      { v4f w; w.x = a0; w.y = a1; w.z = a2; w.w = a3;  \
                    *(v4f*)outp = w; }                              \
        outp += NCOL; }

    #pragma unroll 1
    for (int bt = 0; bt < nrows / 8; ++bt) {
        v4f hi = *(const v4f*)&sp[m - 3];
        v4f lo = *(const v4f*)&sp[m - 7];
        m -= 8;
        STEP(hi.w); EMIT; STEP(hi.z); EMIT; STEP(hi.y); EMIT; STEP(hi.x); EMIT;
        STEP(lo.w); EMIT; STEP(lo.z); EMIT; STEP(lo.y); EMIT; STEP(lo.x); EMIT;
    }
    #pragma unroll 1
    for (int r = nrows & ~7; r < nrows; ++r) {    // tail: 5 rows, last chunk
        float x = sp[m]; --m;
        STEP(x); EMIT;
    }
#undef STEP
#undef EMIT
}

extern "C" void kernel_launch(void* const* d_in, const int* in_sizes, int n_in,
                              void* d_out, int out_size, void* d_ws, size_t ws_size,
                              hipStream_t stream)
{
    const float* score = (const float*)d_in[0];
    const int*   sidx  = (const int*)d_in[1];
    float*       out   = (float*)d_out;

    const int B = in_sizes[0] / LSEQ;    // 32
    dim3 grid(B * 2 * NCHUNK), block(TPB);   // 256 blocks x 256 threads
    gate_kernel<<<grid, block, 0, stream>>>(score, sidx, out);
}